// Round 5
// baseline (489.865 us; speedup 1.0000x reference)
//
#include <hip/hip_runtime.h>
#include <cstdint>
#include <cstddef>

#define DEVFN __device__ __forceinline__

typedef unsigned short u16;
typedef uint32_t u32;
typedef __attribute__((ext_vector_type(8))) short bf16x8;   // 8 bf16 = 4 VGPR (MFMA operand)
typedef __attribute__((ext_vector_type(4))) float f32x4;    // MFMA 16x16 accumulator

constexpr int NB  = 8;
constexpr int NGQ = 4096;
constexpr int NSS = 1024;
constexpr int EE  = 512;
constexpr float SCALING      = 0.0625f;   // 256^-0.5 (folded into Q projection)
constexpr float LAMBDA_INIT_C = 0.2f;     // 0.8 - 0.6*exp(-0.3*0)
constexpr float RMS_EPS_C     = 1e-5f;

DEVFN u16 f2bf(float x) {                  // RNE float -> bf16
  u32 u = __builtin_bit_cast(u32, x);
  u += 0x7FFFu + ((u >> 16) & 1u);
  return (u16)(u >> 16);
}
DEVFN float bf2f(u16 u) { return __builtin_bit_cast(float, (u32)u << 16); }
DEVFN u32 pkf16(float a, float b) {        // pack 2 f32 -> 2 f16 in one u32
  _Float16 ha = (_Float16)a, hb = (_Float16)b;
  return (u32)__builtin_bit_cast(u16, ha) | ((u32)__builtin_bit_cast(u16, hb) << 16);
}
DEVFN float f16lo(u32 v) { return (float)__builtin_bit_cast(_Float16, (u16)(v & 0xffffu)); }
DEVFN float f16hi(u32 v) { return (float)__builtin_bit_cast(_Float16, (u16)(v >> 16)); }

typedef const char __attribute__((address_space(1)))* gas_t;
typedef       char __attribute__((address_space(3)))* las_t;
DEVFN void async16(const void* g, void* l) {   // global -> LDS, 16B/lane, dest = uniform base + lane*16
  __builtin_amdgcn_global_load_lds((gas_t)g, (las_t)l, 16, 0, 0);
}

// ---------------- f32 -> bf16 convert (vectorized, grid-stride) ----------------
__global__ void cvt_kernel(const float* __restrict__ s, u16* __restrict__ d, int n4) {
  int i = blockIdx.x * blockDim.x + threadIdx.x;
  int stride = gridDim.x * blockDim.x;
  for (; i < n4; i += stride) {
    float4 v = ((const float4*)s)[i];
    uint2 p;
    p.x = (u32)f2bf(v.x) | ((u32)f2bf(v.y) << 16);
    p.y = (u32)f2bf(v.z) | ((u32)f2bf(v.w) << 16);
    ((uint2*)d)[i] = p;
  }
}

// 4 weight matrices in one launch (blockIdx.y selects)
__global__ void cvt4_kernel(const float* s0, const float* s1, const float* s2, const float* s3,
                            u16* d0, u16* d1, u16* d2, u16* d3, int n4) {
  const float* sp[4] = {s0, s1, s2, s3};
  u16* dp[4] = {d0, d1, d2, d3};
  const float* s = sp[blockIdx.y];
  u16* d = dp[blockIdx.y];
  int i = blockIdx.x * blockDim.x + threadIdx.x;
  int stride = gridDim.x * blockDim.x;
  for (; i < n4; i += stride) {
    float4 v = ((const float4*)s)[i];
    uint2 p;
    p.x = (u32)f2bf(v.x) | ((u32)f2bf(v.y) << 16);
    p.y = (u32)f2bf(v.z) | ((u32)f2bf(v.w) << 16);
    ((uint2*)d)[i] = p;
  }
}

// ---------------- lambda scalar ----------------
__global__ void lam_kernel(const float* __restrict__ lq1, const float* __restrict__ lk1,
                           const float* __restrict__ lq2, const float* __restrict__ lk2,
                           float* __restrict__ out) {
  int l = threadIdx.x;  // 64 threads
  float s1 = 0.f, s2 = 0.f;
  for (int i = l; i < 256; i += 64) {
    s1 += lq1[i] * lk1[i];
    s2 += lq2[i] * lk2[i];
  }
#pragma unroll
  for (int off = 1; off < 64; off <<= 1) {
    s1 += __shfl_xor(s1, off);
    s2 += __shfl_xor(s2, off);
  }
  if (l == 0) out[0] = __expf(s1) - __expf(s2) + LAMBDA_INIT_C;
}

// ---------------- BT GEMM: C[M,512] = oscale * A[M,512] * W[512,512]^T (bf16 in) ----------------
// 128x128 tile, BK=64, 4 waves (2x2), global_load_lds w/ XOR-swizzled source (T2/rule21).
// OM=0: bf16 C[M,512]. OM=1: bf16 transposed per-1024-row batch: C[b*512+n][m%1024] (V^T).
// OM=2: f32 C[M,512].
template<int OM>
__global__ __launch_bounds__(256, 2) void gemm_bt(const u16* __restrict__ A,
                                                  const u16* __restrict__ W,
                                                  void* __restrict__ Cv, float oscale) {
  __shared__ u16 As[128 * 64];
  __shared__ u16 Bs[128 * 64];
  const int tid = threadIdx.x;
  const int lane = tid & 63, wid = tid >> 6;
  const int lr = lane & 15, lg = lane >> 4;
  const int m0 = blockIdx.x * 128, n0 = blockIdx.y * 128;
  const int wm = wid >> 1, wn = wid & 1;

  f32x4 acc[4][4];
#pragma unroll
  for (int i = 0; i < 4; ++i)
#pragma unroll
    for (int j = 0; j < 4; ++j) acc[i][j] = (f32x4){0.f, 0.f, 0.f, 0.f};

  const int srow = lane >> 3;                  // 0..7 (row within 8-row stage call)
  const int sg   = (lane & 7) ^ srow;          // pre-swizzled source granule

  for (int kt = 0; kt < 512; kt += 64) {
#pragma unroll
    for (int j = 0; j < 4; ++j) {
      int r0 = j * 32 + wid * 8;               // wave-uniform row base
      async16(A + (size_t)(m0 + r0 + srow) * 512 + kt + sg * 8, As + r0 * 64);
      async16(W + (size_t)(n0 + r0 + srow) * 512 + kt + sg * 8, Bs + r0 * 64);
    }
    __syncthreads();
#pragma unroll
    for (int kk = 0; kk < 2; ++kk) {
      bf16x8 av[4], bv[4];
#pragma unroll
      for (int f = 0; f < 4; ++f) {
        int rowa = wm * 64 + f * 16 + lr;
        av[f] = *(const bf16x8*)(As + rowa * 64 + (((kk * 4 + lg) ^ (rowa & 7)) * 8));
        int rowb = wn * 64 + f * 16 + lr;
        bv[f] = *(const bf16x8*)(Bs + rowb * 64 + (((kk * 4 + lg) ^ (rowb & 7)) * 8));
      }
#pragma unroll
      for (int mf = 0; mf < 4; ++mf)
#pragma unroll
        for (int nf = 0; nf < 4; ++nf)
          acc[mf][nf] = __builtin_amdgcn_mfma_f32_16x16x32_bf16(av[mf], bv[nf], acc[mf][nf], 0, 0, 0);
    }
    __syncthreads();
  }

  if (OM == 0) {
    u16* C = (u16*)Cv;
#pragma unroll
    for (int mf = 0; mf < 4; ++mf) {
      int row = m0 + wm * 64 + mf * 16 + lg * 4;
#pragma unroll
      for (int nf = 0; nf < 4; ++nf) {
        int col = n0 + wn * 64 + nf * 16 + lr;
#pragma unroll
        for (int r = 0; r < 4; ++r)
          C[(size_t)(row + r) * 512 + col] = f2bf(acc[mf][nf][r] * oscale);
      }
    }
  } else if (OM == 1) {
    u16* C = (u16*)Cv;
#pragma unroll
    for (int mf = 0; mf < 4; ++mf) {
      int m = m0 + wm * 64 + mf * 16 + lg * 4;   // 4 consecutive m (same batch: 1024%128==0)
      int bb = m >> 10, s = m & 1023;
#pragma unroll
      for (int nf = 0; nf < 4; ++nf) {
        int col = n0 + wn * 64 + nf * 16 + lr;
        uint2 v;
        v.x = (u32)f2bf(acc[mf][nf][0]) | ((u32)f2bf(acc[mf][nf][1]) << 16);
        v.y = (u32)f2bf(acc[mf][nf][2]) | ((u32)f2bf(acc[mf][nf][3]) << 16);
        *(uint2*)(C + ((size_t)(bb * 512 + col)) * 1024 + s) = v;
      }
    }
  } else {
    float* C = (float*)Cv;
#pragma unroll
    for (int mf = 0; mf < 4; ++mf) {
      int row = m0 + wm * 64 + mf * 16 + lg * 4;
#pragma unroll
      for (int nf = 0; nf < 4; ++nf) {
        int col = n0 + wn * 64 + nf * 16 + lr;
#pragma unroll
        for (int r = 0; r < 4; ++r)
          C[(size_t)(row + r) * 512 + col] = acc[mf][nf][r];
      }
    }
  }
}

// ---------------- fused differential attention (single-S-pass + f16 stash) ----------------
// Block: 64 Q-rows x 1 batch, 512 threads (8 waves): qs=wid>>1 (q-stripe of 16), wh=wid&1
// (k-half in S phase / e-half in PV+epilogue). Swapped QK^T: mfma(K,Q) makes each lane's
// softmax row lane-local. Phase 1: S (scaled) -> online (m,l) + stash 2xf16 into diffp.
// Phase 2: readback stash -> final diff f32 in place -> bf16 to Ds -> PV from Vt.
// launch_bounds(512, 2): cap 256 VGPR/wave. (512,4) capped at 128 and strangled ILP:
// VGPR_Count=64, load-use serialization, 12k cyc/barrier-iteration (round-4 post-mortem).
constexpr int CH = 32;                 // kcols per chunk
constexpr int NCH = NSS / CH;          // 32 chunks

__global__ __launch_bounds__(512, 2) void attn_kernel(
    const u16* __restrict__ Qw, const u16* __restrict__ Kw,
    const u16* __restrict__ Vt, const float* __restrict__ rmsw,
    const float* __restrict__ lamp,
    float* __restrict__ diffp, u16* __restrict__ normed) {
  __shared__ u16 Ks[2][CH * 512];       // 2x32KB dbuf, rows=kcol, 512 d, 16B-granule XOR swizzle
  __shared__ u16 Ds[2][64 * CH];        // 2x4KB dbuf diff chunk (bf16 for PV)
  __shared__ float redm[2][4][2][16];
  __shared__ float redl[2][4][2][16];
  __shared__ float red2[64][2];

  const int tid = threadIdx.x;
  const int lane = tid & 63, wid = tid >> 6;
  const int qs = wid >> 1, wh = wid & 1;
  const int lr = lane & 15, lg = lane >> 4;
  const int b = blockIdx.x, qt = blockIdx.y;      // XCD = linear%8 = b -> per-XCD K/V L2 affinity
  const size_t qrb = (size_t)b * NGQ + (size_t)qt * 64;
  const int q = qs * 16 + lr;

  // Q fragments (pre-scaled by 1/16 in projection): lane holds Q[q=lr][d = kk*32 + lg*8 + j]
  bf16x8 qf[2][8];
  {
    const u16* qp = Qw + (qrb + q) * 512;
#pragma unroll
    for (int hd = 0; hd < 2; ++hd)
#pragma unroll
      for (int kk = 0; kk < 8; ++kk)
        qf[hd][kk] = *(const bf16x8*)(qp + hd * 256 + kk * 32 + lg * 8);
  }
  const float lam = lamp[0];
  u32* stash = (u32*)diffp;
  const size_t sbase = (qrb + q) * (size_t)NSS + wh * 16 + lg * 4;

  const u16* kbase = Kw + (size_t)b * NSS * 512;
  const int rowk = wh * 16 + lr;
  const int rx = rowk & 7;

  // ---- phase 1: S both heads, online (m,l), stash f16x2 ----
  // stage chunk 0 (each wave stages 4 of 32 rows)
#pragma unroll
  for (int i = 0; i < 4; ++i) {
    int row = i * 8 + wid;
    async16(kbase + (size_t)row * 512 + (lane ^ (row & 7)) * 8, &Ks[0][row * 512]);
  }

  float mrun[2] = {-3e38f, -3e38f};
  float lrun[2] = {0.f, 0.f};

  for (int c = 0; c < NCH; ++c) {
    // wait own stage_c landed (c>0: tolerate 1 in-flight stash store), then block-wide barrier
    if (c == 0) { asm volatile("s_waitcnt vmcnt(0)" ::: "memory"); }
    else        { asm volatile("s_waitcnt vmcnt(1)" ::: "memory"); }
    __builtin_amdgcn_s_barrier();
    __builtin_amdgcn_sched_barrier(0);
    // prefetch chunk c+1 into other buffer (that buffer's readers all passed the barrier)
    if (c + 1 < NCH) {
      const u16* kb = kbase + (size_t)(c + 1) * CH * 512;
#pragma unroll
      for (int i = 0; i < 4; ++i) {
        int row = i * 8 + wid;
        async16(kb + (size_t)row * 512 + (lane ^ (row & 7)) * 8, &Ks[(c + 1) & 1][row * 512]);
      }
    }
    // compute S on Ks[c&1]
    const u16* kp = &Ks[c & 1][rowk * 512];
    f32x4 s0v = {0.f, 0.f, 0.f, 0.f}, s1v = {0.f, 0.f, 0.f, 0.f};
#pragma unroll
    for (int kk = 0; kk < 8; ++kk) {
      bf16x8 kf0 = *(const bf16x8*)(kp + (((kk * 4 + lg) ^ rx) * 8));
      s0v = __builtin_amdgcn_mfma_f32_16x16x32_bf16(kf0, qf[0][kk], s0v, 0, 0, 0);
      bf16x8 kf1 = *(const bf16x8*)(kp + (((32 + kk * 4 + lg) ^ rx) * 8));
      s1v = __builtin_amdgcn_mfma_f32_16x16x32_bf16(kf1, qf[1][kk], s1v, 0, 0, 0);
    }
    // online stats (S already scaled via Q)
    {
      float mx = fmaxf(fmaxf(s0v[0], s0v[1]), fmaxf(s0v[2], s0v[3]));
      float mn = fmaxf(mrun[0], mx);
      float sc = __expf(mrun[0] - mn);
      lrun[0] = lrun[0] * sc + __expf(s0v[0] - mn) + __expf(s0v[1] - mn)
                             + __expf(s0v[2] - mn) + __expf(s0v[3] - mn);
      mrun[0] = mn;
      mx = fmaxf(fmaxf(s1v[0], s1v[1]), fmaxf(s1v[2], s1v[3]));
      mn = fmaxf(mrun[1], mx);
      sc = __expf(mrun[1] - mn);
      lrun[1] = lrun[1] * sc + __expf(s1v[0] - mn) + __expf(s1v[1] - mn)
                             + __expf(s1v[2] - mn) + __expf(s1v[3] - mn);
      mrun[1] = mn;
    }
    // stash packed f16 scores (head0 lo, head1 hi)
    uint4 pk;
    pk.x = pkf16(s0v[0], s1v[0]);
    pk.y = pkf16(s0v[1], s1v[1]);
    pk.z = pkf16(s0v[2], s1v[2]);
    pk.w = pkf16(s0v[3], s1v[3]);
    *(uint4*)(stash + sbase + (size_t)c * CH) = pk;
  }
  __syncthreads();   // drains vmcnt/lgkm; stats complete

  // ---- merge stats: lane-groups (xor16/32), then across wh halves via LDS ----
  float Mf[2], Li[2];
#pragma unroll
  for (int hd = 0; hd < 2; ++hd) {
    float m = mrun[hd], l = lrun[hd];
#pragma unroll
    for (int off = 16; off < 64; off <<= 1) {
      float mo = __shfl_xor(m, off);
      float lo = __shfl_xor(l, off);
      float mn = fmaxf(m, mo);
      l = l * __expf(m - mn) + lo * __expf(mo - mn);
      m = mn;
    }
    if (lane < 16) { redm[hd][qs][wh][lane] = m; redl[hd][qs][wh][lane] = l; }
  }
  __syncthreads();
#pragma unroll
  for (int hd = 0; hd < 2; ++hd) {
    float ma = redm[hd][qs][0][lr], la = redl[hd][qs][0][lr];
    float mb = redm[hd][qs][1][lr], lb = redl[hd][qs][1][lr];
    float mn = fmaxf(ma, mb);
    float l = la * __expf(ma - mn) + lb * __expf(mb - mn);
    Mf[hd] = mn;
    Li[hd] = 1.f / l;
  }

  // ---- phase 2: readback stash -> diff f32 (in place) -> bf16 Ds -> PV ----
  f32x4 oacc[16];
#pragma unroll
  for (int n = 0; n < 16; ++n) oacc[n] = (f32x4){0.f, 0.f, 0.f, 0.f};

  const u16* vbase = Vt + (size_t)b * 512 * 1024;
  uint4 scur = *(const uint4*)(stash + sbase);

  for (int c = 0; c < NCH; ++c) {
    uint4 snxt = scur;
    if (c + 1 < NCH) snxt = *(const uint4*)(stash + sbase + (size_t)(c + 1) * CH);
    float dd[4];
    {
      float p0, p1;
      p0 = __expf(f16lo(scur.x) - Mf[0]) * Li[0];
      p1 = __expf(f16hi(scur.x) - Mf[1]) * Li[1];
      dd[0] = p0 - lam * p1;
      p0 = __expf(f16lo(scur.y) - Mf[0]) * Li[0];
      p1 = __expf(f16hi(scur.y) - Mf[1]) * Li[1];
      dd[1] = p0 - lam * p1;
      p0 = __expf(f16lo(scur.z) - Mf[0]) * Li[0];
      p1 = __expf(f16hi(scur.z) - Mf[1]) * Li[1];
      dd[2] = p0 - lam * p1;
      p0 = __expf(f16lo(scur.w) - Mf[0]) * Li[0];
      p1 = __expf(f16hi(scur.w) - Mf[1]) * Li[1];
      dd[3] = p0 - lam * p1;
    }
    // final f32 diff_attn, in place over the stash
    *(float4*)(diffp + sbase + (size_t)c * CH) = make_float4(dd[0], dd[1], dd[2], dd[3]);
    // bf16 pack into Ds dbuf (swizzled granules)
    {
      int g16 = wh * 2 + (lg >> 1);                           // data granule (16B = 8 kcols)
      int offs = q * CH + ((g16 ^ (q & 3)) * 8) + (lg & 1) * 4;
      uint2 pk2;
      pk2.x = (u32)f2bf(dd[0]) | ((u32)f2bf(dd[1]) << 16);
      pk2.y = (u32)f2bf(dd[2]) | ((u32)f2bf(dd[3]) << 16);
      *(uint2*)(&Ds[c & 1][0] + offs) = pk2;
    }
    asm volatile("s_waitcnt lgkmcnt(0)" ::: "memory");
    __builtin_amdgcn_s_barrier();
    __builtin_amdgcn_sched_barrier(0);
    // PV: O[q][e] += diff[q][s] * V[s][e]; B-operand straight from Vt (L2-resident per XCD)
    {
      bf16x8 af = *(const bf16x8*)(&Ds[c & 1][0] + q * CH + ((lg ^ (q & 3)) * 8));
      const u16* vb = vbase + c * CH + lg * 8;
      __builtin_amdgcn_s_setprio(1);
#pragma unroll
      for (int n = 0; n < 16; ++n) {
        int er = wh * 256 + n * 16 + lr;
        bf16x8 vf = *(const bf16x8*)(vb + (size_t)er * 1024);
        oacc[n] = __builtin_amdgcn_mfma_f32_16x16x32_bf16(af, vf, oacc[n], 0, 0, 0);
      }
      __builtin_amdgcn_s_setprio(0);
    }
    scur = snxt;
  }
  __syncthreads();

  // ---- epilogue: fused RMSNorm * rms_weight * (1-lambda_init) ----
  float ssq[4] = {0.f, 0.f, 0.f, 0.f};
#pragma unroll
  for (int n = 0; n < 16; ++n)
#pragma unroll
    for (int r = 0; r < 4; ++r) ssq[r] += oacc[n][r] * oacc[n][r];
#pragma unroll
  for (int off = 1; off < 16; off <<= 1)
#pragma unroll
    for (int r = 0; r < 4; ++r) ssq[r] += __shfl_xor(ssq[r], off);
  if (lr == 0) {
#pragma unroll
    for (int r = 0; r < 4; ++r) red2[qs * 16 + lg * 4 + r][wh] = ssq[r];
  }
  __syncthreads();
  float wv[16];
#pragma unroll
  for (int n = 0; n < 16; ++n) wv[n] = rmsw[wh * 256 + n * 16 + lr] * 0.8f;
#pragma unroll
  for (int r = 0; r < 4; ++r) {
    int row = qs * 16 + lg * 4 + r;
    float tot = red2[row][0] + red2[row][1];
    float rs = rsqrtf(tot * (1.f / 512.f) + RMS_EPS_C);
    u16* np = normed + (qrb + row) * 512 + wh * 256 + lr;
#pragma unroll
    for (int n = 0; n < 16; ++n)
      np[n * 16] = f2bf(oacc[n][r] * rs * wv[n]);
  }
}

// ---------------- launch ----------------
extern "C" void kernel_launch(void* const* d_in, const int* in_sizes, int n_in,
                              void* d_out, int out_size, void* d_ws, size_t ws_size,
                              hipStream_t stream) {
  (void)in_sizes; (void)n_in; (void)out_size; (void)ws_size;
  const float* gene = (const float*)d_in[0];
  const float* sub  = (const float*)d_in[1];
  const float* Wq   = (const float*)d_in[2];
  const float* Wk   = (const float*)d_in[3];
  const float* Wv   = (const float*)d_in[4];
  const float* Wo   = (const float*)d_in[5];
  const float* lq1  = (const float*)d_in[6];
  const float* lk1  = (const float*)d_in[7];
  const float* lq2  = (const float*)d_in[8];
  const float* lk2  = (const float*)d_in[9];
  const float* rmsw = (const float*)d_in[10];

  float* outp  = (float*)d_out;
  float* diffp = outp + (size_t)NB * NGQ * EE;   // out first, then diff_attn (f32)

  // bf16 scratch inside d_out's diff region (consumed before attn touches diffp):
  u16* gene_bf = (u16*)diffp;                            // 33.55MB
  u16* sub_bf  = gene_bf + (size_t)NB * NGQ * EE;        //  8.39MB
  u16* Wq_bf   = sub_bf  + (size_t)NB * NSS * EE;
  u16* Wk_bf   = Wq_bf + 262144;
  u16* Wv_bf   = Wk_bf + 262144;

  // ws: lam + Q(=normed alias) + K + Vt + Wo_bf  (~50.9MB)
  char*  ws   = (char*)d_ws;
  float* lamv = (float*)ws;
  u16* Qw = (u16*)(ws + 64);
  u16* Kw = Qw + (size_t)NB * NGQ * EE;
  u16* Vt = Kw + (size_t)NB * NSS * EE;
  u16* Wo_bf = Vt + (size_t)NB * NSS * EE;
  u16* normed = Qw;  // alias: each attn block reads only its own 64 Q rows before writing them

  const int T = 256;
  auto blk = [](int n4) { int b = (n4 + 255) / 256; return b > 2048 ? 2048 : b; };
  cvt_kernel<<<dim3(blk(NB*NGQ*EE/4)), dim3(T), 0, stream>>>(gene, gene_bf, NB*NGQ*EE/4);
  cvt_kernel<<<dim3(blk(NB*NSS*EE/4)), dim3(T), 0, stream>>>(sub,  sub_bf,  NB*NSS*EE/4);
  cvt4_kernel<<<dim3(64, 4), dim3(T), 0, stream>>>(Wq, Wk, Wv, Wo,
                                                   Wq_bf, Wk_bf, Wv_bf, Wo_bf, 65536);
  lam_kernel<<<dim3(1), dim3(64), 0, stream>>>(lq1, lk1, lq2, lk2, lamv);

  gemm_bt<0><<<dim3(256, 4), dim3(256), 0, stream>>>(gene_bf, Wq_bf, Qw, SCALING);
  gemm_bt<0><<<dim3(64, 4),  dim3(256), 0, stream>>>(sub_bf,  Wk_bf, Kw, 1.0f);
  gemm_bt<1><<<dim3(64, 4),  dim3(256), 0, stream>>>(sub_bf,  Wv_bf, Vt, 1.0f);
  attn_kernel<<<dim3(8, 64), dim3(512), 0, stream>>>(Qw, Kw, Vt, rmsw, lamv, diffp, normed);
  gemm_bt<2><<<dim3(256, 4), dim3(256), 0, stream>>>(normed, Wo_bf, outp, 1.0f);
}

// Round 6
// 349.875 us; speedup vs baseline: 1.4001x; 1.4001x over previous
//
#include <hip/hip_runtime.h>
#include <cstdint>
#include <cstddef>

#define DEVFN __device__ __forceinline__

typedef unsigned short u16;
typedef uint32_t u32;
typedef __attribute__((ext_vector_type(8))) short bf16x8;   // 8 bf16 = 4 VGPR (MFMA operand)
typedef __attribute__((ext_vector_type(4))) float f32x4;    // MFMA 16x16 accumulator

constexpr int NB  = 8;
constexpr int NGQ = 4096;
constexpr int NSS = 1024;
constexpr int EE  = 512;
constexpr float SCALING      = 0.0625f;   // 256^-0.5 (folded into Q projection)
constexpr float LAMBDA_INIT_C = 0.2f;     // 0.8 - 0.6*exp(-0.3*0)
constexpr float RMS_EPS_C     = 1e-5f;

DEVFN u16 f2bf(float x) {                  // RNE float -> bf16
  u32 u = __builtin_bit_cast(u32, x);
  u += 0x7FFFu + ((u >> 16) & 1u);
  return (u16)(u >> 16);
}
DEVFN float bf2f(u16 u) { return __builtin_bit_cast(float, (u32)u << 16); }

typedef const char __attribute__((address_space(1)))* gas_t;
typedef       char __attribute__((address_space(3)))* las_t;
DEVFN void async16(const void* g, void* l) {   // global -> LDS, dest = wave-uniform base + lane*16
  __builtin_amdgcn_global_load_lds((gas_t)g, (las_t)l, 16, 0, 0);
}

// ---------------- f32 -> bf16 convert (vectorized, grid-stride) ----------------
__global__ void cvt_kernel(const float* __restrict__ s, u16* __restrict__ d, int n4) {
  int i = blockIdx.x * blockDim.x + threadIdx.x;
  int stride = gridDim.x * blockDim.x;
  for (; i < n4; i += stride) {
    float4 v = ((const float4*)s)[i];
    uint2 p;
    p.x = (u32)f2bf(v.x) | ((u32)f2bf(v.y) << 16);
    p.y = (u32)f2bf(v.z) | ((u32)f2bf(v.w) << 16);
    ((uint2*)d)[i] = p;
  }
}

__global__ void cvt4_kernel(const float* s0, const float* s1, const float* s2, const float* s3,
                            u16* d0, u16* d1, u16* d2, u16* d3, int n4) {
  const float* sp[4] = {s0, s1, s2, s3};
  u16* dp[4] = {d0, d1, d2, d3};
  const float* s = sp[blockIdx.y];
  u16* d = dp[blockIdx.y];
  int i = blockIdx.x * blockDim.x + threadIdx.x;
  int stride = gridDim.x * blockDim.x;
  for (; i < n4; i += stride) {
    float4 v = ((const float4*)s)[i];
    uint2 p;
    p.x = (u32)f2bf(v.x) | ((u32)f2bf(v.y) << 16);
    p.y = (u32)f2bf(v.z) | ((u32)f2bf(v.w) << 16);
    ((uint2*)d)[i] = p;
  }
}

// ---------------- lambda scalar ----------------
__global__ void lam_kernel(const float* __restrict__ lq1, const float* __restrict__ lk1,
                           const float* __restrict__ lq2, const float* __restrict__ lk2,
                           float* __restrict__ out) {
  int l = threadIdx.x;
  float s1 = 0.f, s2 = 0.f;
  for (int i = l; i < 256; i += 64) {
    s1 += lq1[i] * lk1[i];
    s2 += lq2[i] * lk2[i];
  }
#pragma unroll
  for (int off = 1; off < 64; off <<= 1) {
    s1 += __shfl_xor(s1, off);
    s2 += __shfl_xor(s2, off);
  }
  if (l == 0) out[0] = __expf(s1) - __expf(s2) + LAMBDA_INIT_C;
}

// ---------------- BT GEMM: C[M,512] = oscale * A[M,512] * W[512,512]^T (bf16 in) --------
// OM=0: bf16 C[M,512]. OM=1: bf16 chunk-major per-1024-row batch: Vc[b][c=s>>5][e][s&31].
// OM=2: f32 C[M,512].
template<int OM>
__global__ __launch_bounds__(256, 2) void gemm_bt(const u16* __restrict__ A,
                                                  const u16* __restrict__ W,
                                                  void* __restrict__ Cv, float oscale) {
  __shared__ u16 As[128 * 64];
  __shared__ u16 Bs[128 * 64];
  const int tid = threadIdx.x;
  const int lane = tid & 63, wid = tid >> 6;
  const int lr = lane & 15, lg = lane >> 4;
  const int m0 = blockIdx.x * 128, n0 = blockIdx.y * 128;
  const int wm = wid >> 1, wn = wid & 1;

  f32x4 acc[4][4];
#pragma unroll
  for (int i = 0; i < 4; ++i)
#pragma unroll
    for (int j = 0; j < 4; ++j) acc[i][j] = (f32x4){0.f, 0.f, 0.f, 0.f};

  const int srow = lane >> 3;
  const int sg   = (lane & 7) ^ srow;

  for (int kt = 0; kt < 512; kt += 64) {
#pragma unroll
    for (int j = 0; j < 4; ++j) {
      int r0 = j * 32 + wid * 8;
      async16(A + (size_t)(m0 + r0 + srow) * 512 + kt + sg * 8, As + r0 * 64);
      async16(W + (size_t)(n0 + r0 + srow) * 512 + kt + sg * 8, Bs + r0 * 64);
    }
    __syncthreads();
#pragma unroll
    for (int kk = 0; kk < 2; ++kk) {
      bf16x8 av[4], bv[4];
#pragma unroll
      for (int f = 0; f < 4; ++f) {
        int rowa = wm * 64 + f * 16 + lr;
        av[f] = *(const bf16x8*)(As + rowa * 64 + (((kk * 4 + lg) ^ (rowa & 7)) * 8));
        int rowb = wn * 64 + f * 16 + lr;
        bv[f] = *(const bf16x8*)(Bs + rowb * 64 + (((kk * 4 + lg) ^ (rowb & 7)) * 8));
      }
#pragma unroll
      for (int mf = 0; mf < 4; ++mf)
#pragma unroll
        for (int nf = 0; nf < 4; ++nf)
          acc[mf][nf] = __builtin_amdgcn_mfma_f32_16x16x32_bf16(av[mf], bv[nf], acc[mf][nf], 0, 0, 0);
    }
    __syncthreads();
  }

  if (OM == 0) {
    u16* C = (u16*)Cv;
#pragma unroll
    for (int mf = 0; mf < 4; ++mf) {
      int row = m0 + wm * 64 + mf * 16 + lg * 4;
#pragma unroll
      for (int nf = 0; nf < 4; ++nf) {
        int col = n0 + wn * 64 + nf * 16 + lr;
#pragma unroll
        for (int r = 0; r < 4; ++r)
          C[(size_t)(row + r) * 512 + col] = f2bf(acc[mf][nf][r] * oscale);
      }
    }
  } else if (OM == 1) {
    // chunk-major V: Vc[bb][c][e=col][s32], c = s>>5
    u16* C = (u16*)Cv;
#pragma unroll
    for (int mf = 0; mf < 4; ++mf) {
      int m = m0 + wm * 64 + mf * 16 + lg * 4;   // 4 consecutive s, same chunk (s%4==0)
      int bb = m >> 10, s = m & 1023;
      int c = s >> 5, s32 = s & 31;
#pragma unroll
      for (int nf = 0; nf < 4; ++nf) {
        int col = n0 + wn * 64 + nf * 16 + lr;
        uint2 v;
        v.x = (u32)f2bf(acc[mf][nf][0]) | ((u32)f2bf(acc[mf][nf][1]) << 16);
        v.y = (u32)f2bf(acc[mf][nf][2]) | ((u32)f2bf(acc[mf][nf][3]) << 16);
        *(uint2*)(C + (size_t)bb * 524288 + (size_t)c * 16384 + col * 32 + s32) = v;
      }
    }
  } else {
    float* C = (float*)Cv;
#pragma unroll
    for (int mf = 0; mf < 4; ++mf) {
      int row = m0 + wm * 64 + mf * 16 + lg * 4;
#pragma unroll
      for (int nf = 0; nf < 4; ++nf) {
        int col = n0 + wn * 64 + nf * 16 + lr;
#pragma unroll
        for (int r = 0; r < 4; ++r)
          C[(size_t)(row + r) * 512 + col] = acc[mf][nf][r];
      }
    }
  }
}

// ---------------- fused differential attention (two-pass, all-staged) ----------------
// 64 Q-rows x 1 batch per block, 8 waves: qs=wid>>1 (q-stripe), wh=wid&1 (k-half / e-half).
// p1: stats only (K dbuf in LDS, zero stores in loop). p2: recompute S -> diff -> Ds(bf16)
// -> coalesced f32 diff lines + PV from LDS-staged chunk-major V. Counted vmcnt throughout.
constexpr int CH = 32;
constexpr int NCH = NSS / CH;          // 32
constexpr int DSP = 40;                // Ds row pitch (u16): 32 + 8 pad (bank spread)

__global__ __launch_bounds__(512, 2) void attn_kernel(
    const u16* __restrict__ Qw, const u16* __restrict__ Kw,
    const u16* __restrict__ Vc, const float* __restrict__ rmsw,
    const float* __restrict__ lamp,
    float* __restrict__ diffp, u16* __restrict__ normed) {
  __shared__ u16 KV[2][2][CH * 512];    // [dbuf][0:K,1:V][32KB] = 128KB
  __shared__ u16 Ds[2][64 * DSP];       // 10KB dbuf diff chunk (bf16)
  __shared__ float redm[2][4][2][16];
  __shared__ float redl[2][4][2][16];
  __shared__ float red2[64][2];

  const int tid = threadIdx.x;
  const int lane = tid & 63, wid = tid >> 6;
  const int qs = wid >> 1, wh = wid & 1;
  const int lr = lane & 15, lg = lane >> 4;
  const int b = blockIdx.x, qt = blockIdx.y;      // XCD = linear%8 = b -> K/V L2 affinity
  const size_t qrb = (size_t)b * NGQ + (size_t)qt * 64;
  const int q = qs * 16 + lr;

  // Q fragments (pre-scaled): lane holds Q[q=lr][d = kk*32 + lg*8 + j]
  bf16x8 qf[2][8];
  {
    const u16* qp = Qw + (qrb + q) * 512;
#pragma unroll
    for (int hd = 0; hd < 2; ++hd)
#pragma unroll
      for (int kk = 0; kk < 8; ++kk)
        qf[hd][kk] = *(const bf16x8*)(qp + hd * 256 + kk * 32 + lg * 8);
  }
  const float lam = lamp[0];

  const u16* kbase = Kw + (size_t)b * NSS * 512;
  const u16* vbase = Vc + (size_t)b * 524288;
  const int rowk = wh * 16 + lr;
  const int rx = rowk & 7;
  // V staging source indices (per lane): e = k*16 + (lane>>2), granule g' = lane&3
  const int vse  = lane >> 2;                   // e offset within 16-row group
  const int vsg  = (lane & 3) ^ ((lane >> 3) & 3);  // pre-swizzled source granule
  const int vrf  = (lr >> 1) & 3;               // read-side granule XOR key

  // ================= phase 1: stats =================
#pragma unroll
  for (int i = 0; i < 4; ++i) {
    int row = i * 8 + wid;
    async16(kbase + (size_t)row * 512 + (lane ^ (row & 7)) * 8, &KV[0][0][row * 512]);
  }

  float mrun[2] = {-3e38f, -3e38f};
  float lrun[2] = {0.f, 0.f};

  for (int c = 0; c < NCH; ++c) {
    __builtin_amdgcn_s_barrier();        // prev iter's readers of slot (c+1)&1 are done
    {
      int cn = (c + 1) & (NCH - 1);      // wrap: harmless dummy stage on last iter
      const u16* kb = kbase + (size_t)cn * CH * 512;
#pragma unroll
      for (int i = 0; i < 4; ++i) {
        int row = i * 8 + wid;
        async16(kb + (size_t)row * 512 + (lane ^ (row & 7)) * 8, &KV[(c + 1) & 1][0][row * 512]);
      }
    }
    asm volatile("s_waitcnt vmcnt(4)" ::: "memory");   // stage(c) landed; (c+1) in flight
    __builtin_amdgcn_sched_barrier(0);
    const u16* kp = &KV[c & 1][0][rowk * 512];
    f32x4 s0v = {0.f, 0.f, 0.f, 0.f}, s1v = {0.f, 0.f, 0.f, 0.f};
    __builtin_amdgcn_s_setprio(1);
#pragma unroll
    for (int kk = 0; kk < 8; ++kk) {
      bf16x8 kf0 = *(const bf16x8*)(kp + (((kk * 4 + lg) ^ rx) * 8));
      s0v = __builtin_amdgcn_mfma_f32_16x16x32_bf16(kf0, qf[0][kk], s0v, 0, 0, 0);
      bf16x8 kf1 = *(const bf16x8*)(kp + (((32 + kk * 4 + lg) ^ rx) * 8));
      s1v = __builtin_amdgcn_mfma_f32_16x16x32_bf16(kf1, qf[1][kk], s1v, 0, 0, 0);
    }
    __builtin_amdgcn_s_setprio(0);
    {
      float mx = fmaxf(fmaxf(s0v[0], s0v[1]), fmaxf(s0v[2], s0v[3]));
      float mn = fmaxf(mrun[0], mx);
      float sc = __expf(mrun[0] - mn);
      lrun[0] = lrun[0] * sc + __expf(s0v[0] - mn) + __expf(s0v[1] - mn)
                             + __expf(s0v[2] - mn) + __expf(s0v[3] - mn);
      mrun[0] = mn;
      mx = fmaxf(fmaxf(s1v[0], s1v[1]), fmaxf(s1v[2], s1v[3]));
      mn = fmaxf(mrun[1], mx);
      sc = __expf(mrun[1] - mn);
      lrun[1] = lrun[1] * sc + __expf(s1v[0] - mn) + __expf(s1v[1] - mn)
                             + __expf(s1v[2] - mn) + __expf(s1v[3] - mn);
      mrun[1] = mn;
    }
  }
  asm volatile("s_waitcnt vmcnt(0)" ::: "memory");  // drain wrap-stage before p2 reuses KV[0]
  __syncthreads();

  // ---- merge stats ----
  float Mf[2], Li[2];
#pragma unroll
  for (int hd = 0; hd < 2; ++hd) {
    float m = mrun[hd], l = lrun[hd];
#pragma unroll
    for (int off = 16; off < 64; off <<= 1) {
      float mo = __shfl_xor(m, off);
      float lo = __shfl_xor(l, off);
      float mn = fmaxf(m, mo);
      l = l * __expf(m - mn) + lo * __expf(mo - mn);
      m = mn;
    }
    if (lane < 16) { redm[hd][qs][wh][lane] = m; redl[hd][qs][wh][lane] = l; }
  }
  __syncthreads();
#pragma unroll
  for (int hd = 0; hd < 2; ++hd) {
    float ma = redm[hd][qs][0][lr], la = redl[hd][qs][0][lr];
    float mb = redm[hd][qs][1][lr], lb = redl[hd][qs][1][lr];
    float mn = fmaxf(ma, mb);
    float l = la * __expf(ma - mn) + lb * __expf(mb - mn);
    Mf[hd] = mn;
    Li[hd] = 1.f / l;
  }

  // ================= phase 2: recompute S -> diff -> PV =================
  f32x4 oacc[16];
#pragma unroll
  for (int n = 0; n < 16; ++n) oacc[n] = (f32x4){0.f, 0.f, 0.f, 0.f};

  // prestage chunk 0 (K then V: 8 instr/wave)
  {
#pragma unroll
    for (int i = 0; i < 4; ++i) {
      int row = i * 8 + wid;
      async16(kbase + (size_t)row * 512 + (lane ^ (row & 7)) * 8, &KV[0][0][row * 512]);
    }
#pragma unroll
    for (int i = 0; i < 4; ++i) {
      int k = wid * 4 + i;
      int e = k * 16 + vse;
      async16(vbase + (size_t)e * 32 + vsg * 8, &KV[0][1][k * 512]);
    }
  }

  for (int c = 0; c < NCH; ++c) {
    const int bi = c & 1, bn = bi ^ 1;
    __builtin_amdgcn_s_barrier();        // barrier 1: prev iter's slot-bn readers done
    {
      int cn = (c + 1) & (NCH - 1);      // wrap dummy on last iter keeps vmcnt uniform
      const u16* kb = kbase + (size_t)cn * CH * 512;
      const u16* vb = vbase + (size_t)cn * 16384;
#pragma unroll
      for (int i = 0; i < 4; ++i) {
        int row = i * 8 + wid;
        async16(kb + (size_t)row * 512 + (lane ^ (row & 7)) * 8, &KV[bn][0][row * 512]);
      }
#pragma unroll
      for (int i = 0; i < 4; ++i) {
        int k = wid * 4 + i;
        int e = k * 16 + vse;
        async16(vb + (size_t)e * 32 + vsg * 8, &KV[bn][1][k * 512]);
      }
    }
    // wait stage(c): in-flight = stage(c+1)[8] (+ diff store from c-1 [1] when c>0)
    if (c == 0) { asm volatile("s_waitcnt vmcnt(8)" ::: "memory"); }
    else        { asm volatile("s_waitcnt vmcnt(9)" ::: "memory"); }
    __builtin_amdgcn_sched_barrier(0);

    // QK both heads
    const u16* kp = &KV[bi][0][rowk * 512];
    f32x4 s0v = {0.f, 0.f, 0.f, 0.f}, s1v = {0.f, 0.f, 0.f, 0.f};
    __builtin_amdgcn_s_setprio(1);
#pragma unroll
    for (int kk = 0; kk < 8; ++kk) {
      bf16x8 kf0 = *(const bf16x8*)(kp + (((kk * 4 + lg) ^ rx) * 8));
      s0v = __builtin_amdgcn_mfma_f32_16x16x32_bf16(kf0, qf[0][kk], s0v, 0, 0, 0);
      bf16x8 kf1 = *(const bf16x8*)(kp + (((32 + kk * 4 + lg) ^ rx) * 8));
      s1v = __builtin_amdgcn_mfma_f32_16x16x32_bf16(kf1, qf[1][kk], s1v, 0, 0, 0);
    }
    __builtin_amdgcn_s_setprio(0);

    // diff -> Ds (bf16, swizzled granules, padded rows)
    {
      float dd[4];
#pragma unroll
      for (int r = 0; r < 4; ++r) {
        float p0 = __expf(s0v[r] - Mf[0]) * Li[0];
        float p1 = __expf(s1v[r] - Mf[1]) * Li[1];
        dd[r] = p0 - lam * p1;
      }
      int g16 = wh * 2 + (lg >> 1);
      int offs = q * DSP + ((g16 ^ (q & 3)) * 8) + (lg & 1) * 4;
      uint2 pk2;
      pk2.x = (u32)f2bf(dd[0]) | ((u32)f2bf(dd[1]) << 16);
      pk2.y = (u32)f2bf(dd[2]) | ((u32)f2bf(dd[3]) << 16);
      *(uint2*)(&Ds[bi][0] + offs) = pk2;
    }
    asm volatile("s_waitcnt lgkmcnt(0)" ::: "memory");
    __builtin_amdgcn_s_barrier();        // barrier 2: Ds[bi] complete across waves
    __builtin_amdgcn_sched_barrier(0);

    // PV from LDS-staged V
    {
      bf16x8 af = *(const bf16x8*)(&Ds[bi][0] + q * DSP + ((lg ^ (q & 3)) * 8));
      const u16* vsb = &KV[bi][1][0];
      __builtin_amdgcn_s_setprio(1);
#pragma unroll
      for (int n = 0; n < 16; ++n) {
        int e = wh * 256 + n * 16 + lr;
        bf16x8 vf = *(const bf16x8*)(vsb + e * 32 + ((lg ^ vrf) * 8));
        oacc[n] = __builtin_amdgcn_mfma_f32_16x16x32_bf16(af, vf, oacc[n], 0, 0, 0);
      }
      __builtin_amdgcn_s_setprio(0);
    }
    // cooperative f32 diff write: full 128B lines
    {
      int cq = tid >> 3, s8 = tid & 7;
      int slot = (s8 >> 1) ^ (cq & 3);
      uint2 v = *(const uint2*)(&Ds[bi][0] + cq * DSP + slot * 8 + (s8 & 1) * 4);
      float4 f4;
      f4.x = bf2f((u16)(v.x & 0xffffu));
      f4.y = bf2f((u16)(v.x >> 16));
      f4.z = bf2f((u16)(v.y & 0xffffu));
      f4.w = bf2f((u16)(v.y >> 16));
      *(float4*)(diffp + (qrb + cq) * (size_t)NSS + c * CH + s8 * 4) = f4;
    }
  }
  __syncthreads();

  // ---- epilogue: fused RMSNorm * rms_weight * (1-lambda_init) ----
  float ssq[4] = {0.f, 0.f, 0.f, 0.f};
#pragma unroll
  for (int n = 0; n < 16; ++n)
#pragma unroll
    for (int r = 0; r < 4; ++r) ssq[r] += oacc[n][r] * oacc[n][r];
#pragma unroll
  for (int off = 1; off < 16; off <<= 1)
#pragma unroll
    for (int r = 0; r < 4; ++r) ssq[r] += __shfl_xor(ssq[r], off);
  if (lr == 0) {
#pragma unroll
    for (int r = 0; r < 4; ++r) red2[qs * 16 + lg * 4 + r][wh] = ssq[r];
  }
  __syncthreads();
  float wv[16];
#pragma unroll
  for (int n = 0; n < 16; ++n) wv[n] = rmsw[wh * 256 + n * 16 + lr] * 0.8f;
#pragma unroll
  for (int r = 0; r < 4; ++r) {
    int row = qs * 16 + lg * 4 + r;
    float tot = red2[row][0] + red2[row][1];
    float rs = rsqrtf(tot * (1.f / 512.f) + RMS_EPS_C);
    u16* np = normed + (qrb + row) * 512 + wh * 256 + lr;
#pragma unroll
    for (int n = 0; n < 16; ++n)
      np[n * 16] = f2bf(oacc[n][r] * rs * wv[n]);
  }
}

// ---------------- launch ----------------
extern "C" void kernel_launch(void* const* d_in, const int* in_sizes, int n_in,
                              void* d_out, int out_size, void* d_ws, size_t ws_size,
                              hipStream_t stream) {
  (void)in_sizes; (void)n_in; (void)out_size; (void)ws_size;
  const float* gene = (const float*)d_in[0];
  const float* sub  = (const float*)d_in[1];
  const float* Wq   = (const float*)d_in[2];
  const float* Wk   = (const float*)d_in[3];
  const float* Wv   = (const float*)d_in[4];
  const float* Wo   = (const float*)d_in[5];
  const float* lq1  = (const float*)d_in[6];
  const float* lk1  = (const float*)d_in[7];
  const float* lq2  = (const float*)d_in[8];
  const float* lk2  = (const float*)d_in[9];
  const float* rmsw = (const float*)d_in[10];

  float* outp  = (float*)d_out;
  float* diffp = outp + (size_t)NB * NGQ * EE;   // out first, then diff_attn (f32)

  // bf16 scratch inside d_out's diff region (consumed before attn touches diffp):
  u16* gene_bf = (u16*)diffp;
  u16* sub_bf  = gene_bf + (size_t)NB * NGQ * EE;
  u16* Wq_bf   = sub_bf  + (size_t)NB * NSS * EE;
  u16* Wk_bf   = Wq_bf + 262144;
  u16* Wv_bf   = Wk_bf + 262144;

  // ws: lam + Q(=normed alias) + K + Vc + Wo_bf  (~50.9MB)
  char*  ws   = (char*)d_ws;
  float* lamv = (float*)ws;
  u16* Qw = (u16*)(ws + 64);
  u16* Kw = Qw + (size_t)NB * NGQ * EE;
  u16* Vc = Kw + (size_t)NB * NSS * EE;
  u16* Wo_bf = Vc + (size_t)NB * NSS * EE;
  u16* normed = Qw;  // alias: each attn block reads only its own 64 Q rows before writing them

  const int T = 256;
  auto blk = [](int n4) { int b = (n4 + 255) / 256; return b > 2048 ? 2048 : b; };
  cvt_kernel<<<dim3(blk(NB*NGQ*EE/4)), dim3(T), 0, stream>>>(gene, gene_bf, NB*NGQ*EE/4);
  cvt_kernel<<<dim3(blk(NB*NSS*EE/4)), dim3(T), 0, stream>>>(sub,  sub_bf,  NB*NSS*EE/4);
  cvt4_kernel<<<dim3(64, 4), dim3(T), 0, stream>>>(Wq, Wk, Wv, Wo,
                                                   Wq_bf, Wk_bf, Wv_bf, Wo_bf, 65536);
  lam_kernel<<<dim3(1), dim3(64), 0, stream>>>(lq1, lk1, lq2, lk2, lamv);

  gemm_bt<0><<<dim3(256, 4), dim3(256), 0, stream>>>(gene_bf, Wq_bf, Qw, SCALING);
  gemm_bt<0><<<dim3(64, 4),  dim3(256), 0, stream>>>(sub_bf,  Wk_bf, Kw, 1.0f);
  gemm_bt<1><<<dim3(64, 4),  dim3(256), 0, stream>>>(sub_bf,  Wv_bf, Vc, 1.0f);
  attn_kernel<<<dim3(8, 64), dim3(512), 0, stream>>>(Qw, Kw, Vc, rmsw, lamv, diffp, normed);
  gemm_bt<2><<<dim3(256, 4), dim3(256), 0, stream>>>(normed, Wo_bf, outp, 1.0f);
}